// Round 1
// 343.295 us; speedup vs baseline: 1.0768x; 1.0768x over previous
//
#include <hip/hip_runtime.h>
#include <math.h>

// Problem constants (match reference)
#define GRID_ 256
#define P_    16     // source patch side
#define PH_   16     // patches per side
#define N_    256    // patches
#define S_    256    // source pixels / patch
#define T_    256    // target pixels / patch
#define B_    4
#define TEMP_INV 10.0f
#define LN_EPS   1e-5f

// Native vector type: __builtin_nontemporal_load requires scalar/vector,
// and HIP's float4 is a struct wrapper.
typedef float f32x4 __attribute__((ext_vector_type(4)));

__device__ __forceinline__ f32x4 ldnt4(const float* p) {
    return __builtin_nontemporal_load((const f32x4*)p);
}

// One block per (b, n). 256 threads = 4 waves.
// Matvec as 16-lane row-groups: wave = 4 groups x 16 lanes.
// Per tile-pair (8 rows/wave): 8 coalesced 16B nt-loads, 32 FMAs, 8 shfl.
// Explicit 2-deep double buffer (wvA/wvB, statically indexed) keeps the
// next 8 loads in flight while the current FMA+shfl chain drains, and
// `nt` skips cache allocation for the 256 MiB single-use W stream.
__global__ __launch_bounds__(256, 4) void axonal_kernel(
    const float* __restrict__ spikes,   // [B, 256, 256]
    const float* __restrict__ W,        // [B, N, T, S]
    const float* __restrict__ g_ln,     // [T] gamma
    const float* __restrict__ b_ln,     // [T] beta
    const float* __restrict__ gates,    // [N]
    const float* __restrict__ biases,   // [N]
    float* __restrict__ out)            // [B, 256, 256]
{
    const int n    = blockIdx.x;
    const int b    = blockIdx.y;
    const int tid  = threadIdx.x;
    const int lane = tid & 63;
    const int wid  = tid >> 6;
    const int lg   = lane & 15;   // column-chunk lane within row group
    const int g    = lane >> 4;   // row group (0..3)

    __shared__ float s_out[T_];
    __shared__ float s_red[8];

    const int pi = n >> 4, pj = n & 15;

    // ---- spike fragments: spq[q] = sp[q*64 + lg*4 .. +3] (same in all groups)
    // unfold: sp[s = ii*16 + jj] = spikes[b][pi*16+ii][pj*16+jj]
    f32x4 spq[4];
    #pragma unroll
    for (int q = 0; q < 4; ++q) {
        const int s  = q * 64 + lg * 4;
        const int ii = s >> 4;
        const int jj = s & 15;
        spq[q] = *(const f32x4*)(
            spikes + (((size_t)b * GRID_ + pi * P_ + ii) * GRID_ + pj * P_ + jj));
    }

    // spike sum: each lg covers distinct s; reduce over the 16-lane group
    float spsum = 0.0f;
    #pragma unroll
    for (int q = 0; q < 4; ++q)
        spsum += spq[q].x + spq[q].y + spq[q].z + spq[q].w;
    #pragma unroll
    for (int off = 1; off < 16; off <<= 1)
        spsum += __shfl_xor(spsum, off, 64);

    const float* Wbn = W + ((size_t)(b * N_ + n)) * T_ * S_;

    // ---- matvec: wave `wid` computes rows t = wid*64 .. wid*64+63 ----
    // 8 tile-pairs of 8 rows each; rows of pair tp: r0 = wid*64 + tp*8,
    // this lane handles rows r0+g (->p0) and r0+4+g (->p1).
    const float* rowp = Wbn + (size_t)((wid << 6) + g) * S_ + lg * 4;

    f32x4 wvA[8], wvB[8];

    #define LOADT(buf, tp)                                                    \
        _Pragma("unroll")                                                     \
        for (int u = 0; u < 2; ++u) {                                         \
            _Pragma("unroll")                                                 \
            for (int q = 0; q < 4; ++q)                                       \
                buf[u * 4 + q] =                                              \
                    ldnt4(rowp + (size_t)((tp) * 8 + u * 4) * S_ + q * 64);   \
        }

    #define COMPT(buf, tp)                                                    \
        {                                                                     \
            float p0 = 0.0f, p1 = 0.0f;                                       \
            _Pragma("unroll")                                                 \
            for (int q = 0; q < 4; ++q) {                                     \
                p0 += buf[q].x     * spq[q].x + buf[q].y     * spq[q].y       \
                    + buf[q].z     * spq[q].z + buf[q].w     * spq[q].w;      \
                p1 += buf[4 + q].x * spq[q].x + buf[4 + q].y * spq[q].y       \
                    + buf[4 + q].z * spq[q].z + buf[4 + q].w * spq[q].w;      \
            }                                                                 \
            _Pragma("unroll")                                                 \
            for (int off = 1; off < 16; off <<= 1) {                          \
                p0 += __shfl_xor(p0, off, 64);                                \
                p1 += __shfl_xor(p1, off, 64);                                \
            }                                                                 \
            if (lg == 0) {                                                    \
                const int r0 = (wid << 6) + (tp) * 8;                         \
                s_out[r0 + g]     = p0;                                       \
                s_out[r0 + 4 + g] = p1;                                       \
            }                                                                 \
        }

    LOADT(wvA, 0)
    #pragma unroll
    for (int i = 0; i < 4; ++i) {
        LOADT(wvB, 2 * i + 1)
        COMPT(wvA, 2 * i)
        if (i < 3) { LOADT(wvA, 2 * i + 2) }
        COMPT(wvB, 2 * i + 1)
    }

    #undef LOADT
    #undef COMPT

    __syncthreads();

    // ---- phase 2: LayerNorm + softmax + scale, one thread per t ----
    const int t = tid;
    const float val = s_out[t];

    // block reduce: sum and sumsq
    float s1 = val, s2 = val * val;
    #pragma unroll
    for (int off = 32; off; off >>= 1) {
        s1 += __shfl_xor(s1, off, 64);
        s2 += __shfl_xor(s2, off, 64);
    }
    if (lane == 0) { s_red[wid] = s1; s_red[4 + wid] = s2; }
    __syncthreads();
    const float sum1 = s_red[0] + s_red[1] + s_red[2] + s_red[3];
    const float sum2 = s_red[4] + s_red[5] + s_red[6] + s_red[7];
    const float mean = sum1 * (1.0f / T_);
    const float var  = sum2 * (1.0f / T_) - mean * mean;
    const float rstd = rsqrtf(var + LN_EPS);
    const float z = ((val - mean) * rstd * g_ln[t] + b_ln[t]) * TEMP_INV;

    // block reduce: max
    float m = z;
    #pragma unroll
    for (int off = 32; off; off >>= 1) m = fmaxf(m, __shfl_xor(m, off, 64));
    __syncthreads();                  // all reads of s_red done before reuse
    if (lane == 0) s_red[wid] = m;
    __syncthreads();
    m = fmaxf(fmaxf(s_red[0], s_red[1]), fmaxf(s_red[2], s_red[3]));

    // block reduce: sum of exp
    const float e = __expf(z - m);
    float es = e;
    #pragma unroll
    for (int off = 32; off; off >>= 1) es += __shfl_xor(es, off, 64);
    __syncthreads();
    if (lane == 0) s_red[wid] = es;
    __syncthreads();
    const float esum = s_red[0] + s_red[1] + s_red[2] + s_red[3];

    const float scal = gates[n] * spsum + biases[n];
    const float fin  = (e / esum) * scal;

    // fold: out[b][pi*16 + ti][pj*16 + tj] = final[b][n][t], t = ti*16 + tj
    const int ti = t >> 4, tj = t & 15;
    __builtin_nontemporal_store(
        fin, out + ((size_t)b * GRID_ + pi * P_ + ti) * GRID_ + pj * P_ + tj);
}

extern "C" void kernel_launch(void* const* d_in, const int* in_sizes, int n_in,
                              void* d_out, int out_size, void* d_ws, size_t ws_size,
                              hipStream_t stream) {
    const float* spikes = (const float*)d_in[0];
    const float* W      = (const float*)d_in[1];
    const float* g_ln   = (const float*)d_in[2];
    const float* b_ln   = (const float*)d_in[3];
    const float* gates  = (const float*)d_in[4];
    const float* biases = (const float*)d_in[5];
    float* out = (float*)d_out;

    dim3 grid(N_, B_);
    dim3 block(256);
    axonal_kernel<<<grid, block, 0, stream>>>(spikes, W, g_ln, b_ln,
                                              gates, biases, out);
}